// Round 6
// baseline (246.889 us; speedup 1.0000x reference)
//
#include <hip/hip_runtime.h>

#define HI 1440
#define WI 1920
#define NPIX (HI*WI)
#define EPSF 1e-8f

#define GCOLS 52            // valid output columns per wave
#define NG 37               // ceil(1920/52)
#define SROWS 15            // output rows per strip
#define NS 96               // 1440/15 exact
#define NWAVES (NG*NS)      // 3552
#define NBLOCKS (NWAVES/4)  // 888
#define PROWS 28            // raw rows per strip (mult of 7, >= SROWS+13)

typedef __fp16 h2 __attribute__((ext_vector_type(2)));

// ---------------- small 3x3 helpers ----------------
__device__ __forceinline__ void mat3mul(const float* A, const float* B, float* C) {
#pragma unroll
  for (int i = 0; i < 3; ++i)
#pragma unroll
    for (int j = 0; j < 3; ++j)
      C[i*3+j] = A[i*3+0]*B[0+j] + A[i*3+1]*B[3+j] + A[i*3+2]*B[6+j];
}

__device__ void rodrigues_dev(const float* v, float* R) {
  float th = sqrtf(v[0]*v[0] + v[1]*v[1] + v[2]*v[2]) + 1e-12f;
  float kx = v[0]/th, ky = v[1]/th, kz = v[2]/th;
  float st = sinf(th), ct = cosf(th);
  float S[9] = {0.f,-kz,ky, kz,0.f,-kx, -ky,kx,0.f};
  float S2[9];
  mat3mul(S, S, S2);
#pragma unroll
  for (int i = 0; i < 9; ++i) R[i] = st*S[i] + (1.f-ct)*S2[i];
  R[0] += 1.f; R[4] += 1.f; R[8] += 1.f;
}

// compute per-target M[12]: B = K*Rt*R1^T*Kinv (9) and a = K*Rt*(C1-Ct) (3); [24]=f
__device__ void make_mats(float f, const float* aa, const float* cen, float* m) {
  const float u0 = WI*0.5f - 0.5f;
  const float v0 = HI*0.5f - 0.5f;
  float K[9]  = {f,0.f,u0, 0.f,f,v0, 0.f,0.f,1.f};
  float Ki[9] = {1.f/f,0.f,-u0/f, 0.f,1.f/f,-v0/f, 0.f,0.f,1.f};
  float R1[9]; rodrigues_dev(aa, R1);
  float R1T[9];
  for (int i = 0; i < 3; ++i)
    for (int j = 0; j < 3; ++j) R1T[i*3+j] = R1[j*3+i];
  for (int t = 0; t < 2; ++t) {
    float Rt[9]; rodrigues_dev(aa + 3*(t+1), Rt);
    float A[9]; mat3mul(K, Rt, A);
    float Tm[9]; mat3mul(A, R1T, Tm);
    float B[9]; mat3mul(Tm, Ki, B);
    float Cd[3] = {cen[0]-cen[3*(t+1)+0], cen[1]-cen[3*(t+1)+1], cen[2]-cen[3*(t+1)+2]};
    float* M = m + t*12;
    for (int i = 0; i < 9; ++i) M[i] = B[i];
    M[9]  = A[0]*Cd[0]+A[1]*Cd[1]+A[2]*Cd[2];
    M[10] = A[3]*Cd[0]+A[4]*Cd[1]+A[5]*Cd[2];
    M[11] = A[6]*Cd[0]+A[7]*Cd[1]+A[8]*Cd[2];
  }
  m[24] = f;
}

__device__ __forceinline__ float bilerp(const float* __restrict__ img, float px, float py) {
  float x0 = floorf(px), y0 = floorf(py);
  float wx = px - x0, wy = py - y0;
  float x1 = x0 + 1.f, y1 = y0 + 1.f;
  const float xmax = (float)(WI-1), ymax = (float)(HI-1);
  bool bx0 = (x0 >= 0.f) && (x0 <= xmax);
  bool bx1 = (x1 >= 0.f) && (x1 <= xmax);
  bool by0 = (y0 >= 0.f) && (y0 <= ymax);
  bool by1 = (y1 >= 0.f) && (y1 <= ymax);
  float v00 = 0.f, v10 = 0.f, v01 = 0.f, v11 = 0.f;
  if (bx0 && by0) v00 = img[(int)y0*WI + (int)x0];
  if (bx1 && by0) v10 = img[(int)y0*WI + (int)x1];
  if (bx0 && by1) v01 = img[(int)y1*WI + (int)x0];
  if (bx1 && by1) v11 = img[(int)y1*WI + (int)x1];
  return (1.f-wy)*((1.f-wx)*v00 + wx*v10) + wy*((1.f-wx)*v01 + wx*v11);
}

// K1: per-pixel warp + gather, store fp16-packed (w0,w1). Each block builds
// mats in LDS (thread 0). Global thread 0 also zeroes the K2 accumulators.
__global__ __launch_bounds__(256) void k_warp(const float* __restrict__ focal,
                                              const float* __restrict__ aa,
                                              const float* __restrict__ cen,
                                              const float* __restrict__ depth,
                                              const float* __restrict__ tgts,
                                              unsigned int* __restrict__ wpk,
                                              float* __restrict__ acc) {
  __shared__ float sm[25];
  if (threadIdx.x == 0) {
    make_mats(focal[0], aa, cen, sm);
    if (blockIdx.x == 0) {
      acc[0] = 0.f; acc[1] = 0.f;
      ((unsigned int*)acc)[2] = 0u;
    }
  }
  __syncthreads();
  const int idx = blockIdx.x*256 + threadIdx.x;
  const int y = idx / WI, x = idx - y*WI;
  const float f = sm[24];

  float d  = depth[idx];
  float dl = (x > 0)    ? depth[idx-1]  : 0.f;
  float dr = (x < WI-1) ? depth[idx+1]  : 0.f;
  float dt = (y > 0)    ? depth[idx-WI] : 0.f;
  float db = (y < HI-1) ? depth[idx+WI] : 0.f;
  float du = 0.5f*(dr - dl);
  float dv = 0.5f*(db - dt);
  float fx = (float)x, fy = (float)y;
  float nx = f*du, ny = f*dv;
  float nz = (960.f - fx)*du + (720.f - fy)*dv - d;
  float nn = sqrtf(nx*nx + ny*ny + nz*nz) + EPSF;
  float wsc = 1.f/(nn*(d + EPSF));
  float px = (fx - 959.5f)/f, py = (fy - 719.5f)/f;
  float sv = (nx*px + ny*py + nz)*wsc;
  float w0, w1;
  {
    float a0 = sm[0]*fx + sm[1]*fy + sm[2] + sm[9]*sv;
    float a1 = sm[3]*fx + sm[4]*fy + sm[5] + sm[10]*sv;
    float a2 = sm[6]*fx + sm[7]*fy + sm[8] + sm[11]*sv;
    float iz = 1.f/(a2 + EPSF);
    w0 = bilerp(tgts, a0*iz, a1*iz);
  }
  {
    float a0 = sm[12]*fx + sm[13]*fy + sm[14] + sm[21]*sv;
    float a1 = sm[15]*fx + sm[16]*fy + sm[17] + sm[22]*sv;
    float a2 = sm[18]*fx + sm[19]*fy + sm[20] + sm[23]*sv;
    float iz = 1.f/(a2 + EPSF);
    w1 = bilerp(tgts + NPIX, a0*iz, a1*iz);
  }
  wpk[idx] = __builtin_bit_cast(unsigned int, __builtin_amdgcn_cvt_pkrtz(w0, w1));
}

__device__ __forceinline__ float hsum7(float v, int ln) {
  float a = __shfl(v, ln-3, 64), b = __shfl(v, ln-2, 64), c = __shfl(v, ln-1, 64);
  float d = __shfl(v, ln+1, 64), e = __shfl(v, ln+2, 64), g = __shfl(v, ln+3, 64);
  return ((a + b) + (c + v)) + ((d + e) + g);
}

__device__ __forceinline__ h2 hsum7p(h2 v, int ln) {
  int vi = __builtin_bit_cast(int, v);
  h2 a = __builtin_bit_cast(h2, __shfl(vi, ln-3, 64));
  h2 b = __builtin_bit_cast(h2, __shfl(vi, ln-2, 64));
  h2 c = __builtin_bit_cast(h2, __shfl(vi, ln-1, 64));
  h2 d = __builtin_bit_cast(h2, __shfl(vi, ln+1, 64));
  h2 e = __builtin_bit_cast(h2, __shfl(vi, ln+2, 64));
  h2 g = __builtin_bit_cast(h2, __shfl(vi, ln+3, 64));
  return ((a + b) + (c + v)) + ((d + e) + g);
}

// K2: wave-streaming ZNCC over precomputed warped planes. One wave = strip of
// 15 output rows x 52 cols, both targets. Rows are cheap: 2 coalesced loads +
// 30 shuffles + running sums. Ends with device atomics + last-block finisher.
__global__ __launch_bounds__(256) void k_zncc(const float* __restrict__ ref,
                                              const unsigned int* __restrict__ wpk,
                                              float* __restrict__ acc,
                                              float* __restrict__ out) {
  const int wid = blockIdx.x*4 + (threadIdx.x >> 6);
  const int ln = threadIdx.x & 63;
  const int g = wid % NG, st = wid / NG;
  const int R0 = st * SROWS;
  const int x = g*GCOLS - 6 + ln;
  const bool xok = (x >= 0) && (x < WI);

  float rring[7];
  h2 wring[7];
  float Hr[7], H0[7], H1[7];
  float Qrr[7], Qrt0[7], Qtt0[7], Qrt1[7], Qtt1[7];
  const h2 hz = {(__fp16)0.f, (__fp16)0.f};
#pragma unroll
  for (int k = 0; k < 7; ++k) {
    rring[k]=0.f; wring[k]=hz;
    Hr[k]=0.f; H0[k]=0.f; H1[k]=0.f;
    Qrr[k]=0.f; Qrt0[k]=0.f; Qtt0[k]=0.f; Qrt1[k]=0.f; Qtt1[k]=0.f;
  }
  float Sr=0.f, S0=0.f, S1=0.f;
  float Vrr=0.f, Vrt0=0.f, Vtt0=0.f, Vrt1=0.f, Vtt1=0.f;
  float acc_s=0.f, acc_c=0.f;

  for (int ib = 0; ib < PROWS; ib += 7) {
#pragma unroll
    for (int j = 0; j < 7; ++j) {
      const int y = R0 - 6 + ib + j;

      // ---- loads (coalesced) ----
      float r = 0.f;
      h2 wp = hz;
      if (xok && y >= 0 && y < HI) {
        const int gidx = y*WI + x;
        r = ref[gidx];
        wp = __builtin_bit_cast(h2, wpk[gidx]);
      }
      rring[j] = r;
      wring[j] = wp;

      // ---- horizontal 7-sums of raw planes ----
      float hr = hsum7(r, ln);
      h2 hw = hsum7p(wp, ln);
      float h0 = (float)hw.x, h1 = (float)hw.y;

      // ---- vertical running box sums; box complete at yc = y-3 ----
      Sr += hr; S0 += h0; S1 += h1;
      const float Br = Sr, B0 = S0, B1 = S1;
      Sr -= Hr[(j+1)%7]; S0 -= H0[(j+1)%7]; S1 -= H1[(j+1)%7];
      Hr[j] = hr; H0[j] = h0; H1[j] = h1;

      // ---- centered values at row yc ----
      const int yc = y - 3;
      float cr = 0.f, c0 = 0.f, c1 = 0.f;
      if (xok && yc >= 0 && yc < HI) {
        h2 wc = wring[(j+4)%7];
        cr = rring[(j+4)%7] - Br*(1.f/49.f);
        c0 = (float)wc.x - B0*(1.f/49.f);
        c1 = (float)wc.y - B1*(1.f/49.f);
      }

      // ---- product horizontal 7-sums ----
      float prr = hsum7(cr*cr, ln);
      h2 q0 = hsum7p(__builtin_amdgcn_cvt_pkrtz(cr*c0, c0*c0), ln);
      h2 q1 = hsum7p(__builtin_amdgcn_cvt_pkrtz(cr*c1, c1*c1), ln);
      float hrt0 = (float)q0.x, htt0 = (float)q0.y;
      float hrt1 = (float)q1.x, htt1 = (float)q1.y;

      // ---- vertical running window sums; window complete at yo = y-6 ----
      Vrr += prr; Vrt0 += hrt0; Vtt0 += htt0; Vrt1 += hrt1; Vtt1 += htt1;

      const int yo = y - 6;
      if (yo >= R0 && yo < R0 + SROWS && ln >= 6 && ln <= 57 && x < WI) {
        const int mb = __builtin_bit_cast(int, wring[(j+1)%7]);  // raw w at row yo
        const float inv49 = 1.f/49.f;
        float vr = Vrr*inv49;
        if (mb & 0xffff) {
          float zm = (Vrt0*inv49) * rsqrtf(vr*(Vtt0*inv49) + EPSF);
          acc_s += zm; acc_c += 1.f;
        }
        if (((unsigned)mb >> 16) != 0u) {
          float zm = (Vrt1*inv49) * rsqrtf(vr*(Vtt1*inv49) + EPSF);
          acc_s += zm; acc_c += 1.f;
        }
      }

      Vrr -= Qrr[(j+5)%7]; Vrt0 -= Qrt0[(j+5)%7]; Vtt0 -= Qtt0[(j+5)%7];
      Vrt1 -= Qrt1[(j+5)%7]; Vtt1 -= Qtt1[(j+5)%7];
      Qrr[(j+4)%7] = prr; Qrt0[(j+4)%7] = hrt0; Qtt0[(j+4)%7] = htt0;
      Qrt1[(j+4)%7] = hrt1; Qtt1[(j+4)%7] = htt1;
    }
  }

  // ---- wave reduce + device atomics ----
#pragma unroll
  for (int off = 32; off > 0; off >>= 1) {
    acc_s += __shfl_down(acc_s, off, 64);
    acc_c += __shfl_down(acc_c, off, 64);
  }
  if (ln == 0) {
    atomicAdd(&acc[0], acc_s);
    atomicAdd(&acc[1], acc_c);
  }
  __syncthreads();
  if (threadIdx.x == 0) {
    __threadfence();
    unsigned int old = atomicAdd(&((unsigned int*)acc)[2], 1u);
    if (old == NBLOCKS - 1) {           // last block: finish
      float S = atomicAdd(&acc[0], 0.f);
      float C = atomicAdd(&acc[1], 0.f);
      float mean = S / fmaxf(C, 1.f);
      out[0] = (C > 0.f) ? 0.5f*(1.f - mean) : 0.f;
    }
  }
}

extern "C" void kernel_launch(void* const* d_in, const int* in_sizes, int n_in,
                              void* d_out, int out_size, void* d_ws, size_t ws_size,
                              hipStream_t stream) {
  const float* focal  = (const float*)d_in[0];
  const float* aa     = (const float*)d_in[1];
  const float* cen    = (const float*)d_in[2];
  const float* ref    = (const float*)d_in[3];
  const float* depth  = (const float*)d_in[4];
  const float* tgts   = (const float*)d_in[5];
  float* out = (float*)d_out;

  float* acc = (float*)d_ws;                           // [0]=S, [1]=C, [2]=counter
  unsigned int* wpk = (unsigned int*)((float*)d_ws + 8);  // N dwords

  k_warp<<<NPIX/256, 256, 0, stream>>>(focal, aa, cen, depth, tgts, wpk, acc);
  k_zncc<<<NBLOCKS, 256, 0, stream>>>(ref, wpk, acc, out);
}

// Round 7
// 188.257 us; speedup vs baseline: 1.3114x; 1.3114x over previous
//
#include <hip/hip_runtime.h>

#define HI 1440
#define WI 1920
#define NPIX (HI*WI)
#define EPSF 1e-8f

#define GCOLS 52            // valid output columns per wave
#define NG 37               // ceil(1920/52)
#define SROWS 15            // output rows per strip
#define NS 96               // 1440/15 exact
#define NWAVES (NG*NS)      // 3552
#define PROWS 28            // raw rows per strip (mult of 7, >= SROWS+13)

typedef __fp16 h2 __attribute__((ext_vector_type(2)));

// ---------------- small 3x3 helpers ----------------
__device__ __forceinline__ void mat3mul(const float* A, const float* B, float* C) {
#pragma unroll
  for (int i = 0; i < 3; ++i)
#pragma unroll
    for (int j = 0; j < 3; ++j)
      C[i*3+j] = A[i*3+0]*B[0+j] + A[i*3+1]*B[3+j] + A[i*3+2]*B[6+j];
}

__device__ __forceinline__ void rodrigues_dev(const float* v, float* R) {
  float th = sqrtf(v[0]*v[0] + v[1]*v[1] + v[2]*v[2]) + 1e-12f;
  float kx = v[0]/th, ky = v[1]/th, kz = v[2]/th;
  float st = sinf(th), ct = cosf(th);
  float S[9] = {0.f,-kz,ky, kz,0.f,-kx, -ky,kx,0.f};
  float S2[9];
  mat3mul(S, S, S2);
#pragma unroll
  for (int i = 0; i < 9; ++i) R[i] = st*S[i] + (1.f-ct)*S2[i];
  R[0] += 1.f; R[4] += 1.f; R[8] += 1.f;
}

// per-target M[12]: B = K*Rt*R1^T*Kinv (9) and a = K*Rt*(C1-Ct) (3)
__device__ void make_mats(float f, const float* __restrict__ aa,
                          const float* __restrict__ cen, float* m) {
  const float u0 = WI*0.5f - 0.5f;
  const float v0 = HI*0.5f - 0.5f;
  float K[9]  = {f,0.f,u0, 0.f,f,v0, 0.f,0.f,1.f};
  float Ki[9] = {1.f/f,0.f,-u0/f, 0.f,1.f/f,-v0/f, 0.f,0.f,1.f};
  float R1[9]; rodrigues_dev(aa, R1);
  float R1T[9];
#pragma unroll
  for (int i = 0; i < 3; ++i)
#pragma unroll
    for (int j = 0; j < 3; ++j) R1T[i*3+j] = R1[j*3+i];
#pragma unroll
  for (int t = 0; t < 2; ++t) {
    float Rt[9]; rodrigues_dev(aa + 3*(t+1), Rt);
    float A[9]; mat3mul(K, Rt, A);
    float Tm[9]; mat3mul(A, R1T, Tm);
    float B[9]; mat3mul(Tm, Ki, B);
    float Cd[3] = {cen[0]-cen[3*(t+1)+0], cen[1]-cen[3*(t+1)+1], cen[2]-cen[3*(t+1)+2]};
    float* M = m + t*12;
#pragma unroll
    for (int i = 0; i < 9; ++i) M[i] = B[i];
    M[9]  = A[0]*Cd[0]+A[1]*Cd[1]+A[2]*Cd[2];
    M[10] = A[3]*Cd[0]+A[4]*Cd[1]+A[5]*Cd[2];
    M[11] = A[6]*Cd[0]+A[7]*Cd[1]+A[8]*Cd[2];
  }
}

__device__ __forceinline__ float bilerp(const float* __restrict__ img, float px, float py) {
  float x0 = floorf(px), y0 = floorf(py);
  float wx = px - x0, wy = py - y0;
  float x1 = x0 + 1.f, y1 = y0 + 1.f;
  const float xmax = (float)(WI-1), ymax = (float)(HI-1);
  bool bx0 = (x0 >= 0.f) && (x0 <= xmax);
  bool bx1 = (x1 >= 0.f) && (x1 <= xmax);
  bool by0 = (y0 >= 0.f) && (y0 <= ymax);
  bool by1 = (y1 >= 0.f) && (y1 <= ymax);
  float v00 = 0.f, v10 = 0.f, v01 = 0.f, v11 = 0.f;
  if (bx0 && by0) v00 = img[(int)y0*WI + (int)x0];
  if (bx1 && by0) v10 = img[(int)y0*WI + (int)x1];
  if (bx0 && by1) v01 = img[(int)y1*WI + (int)x0];
  if (bx1 && by1) v11 = img[(int)y1*WI + (int)x1];
  return (1.f-wy)*((1.f-wx)*v00 + wx*v10) + wy*((1.f-wx)*v01 + wx*v11);
}

__device__ __forceinline__ float hsum7(float v, int ln) {
  float a = __shfl(v, ln-3, 64), b = __shfl(v, ln-2, 64), c = __shfl(v, ln-1, 64);
  float d = __shfl(v, ln+1, 64), e = __shfl(v, ln+2, 64), g = __shfl(v, ln+3, 64);
  return ((a + b) + (c + v)) + ((d + e) + g);
}

__device__ __forceinline__ h2 hsum7p(h2 v, int ln) {
  int vi = __builtin_bit_cast(int, v);
  h2 a = __builtin_bit_cast(h2, __shfl(vi, ln-3, 64));
  h2 b = __builtin_bit_cast(h2, __shfl(vi, ln-2, 64));
  h2 c = __builtin_bit_cast(h2, __shfl(vi, ln-1, 64));
  h2 d = __builtin_bit_cast(h2, __shfl(vi, ln+1, 64));
  h2 e = __builtin_bit_cast(h2, __shfl(vi, ln+2, 64));
  h2 g = __builtin_bit_cast(h2, __shfl(vi, ln+3, 64));
  return ((a + b) + (c + v)) + ((d + e) + g);
}

__device__ __forceinline__ float loadI(const float* __restrict__ p, int x, int y) {
  return (x >= 0 && x < WI && y >= 0 && y < HI) ? p[y*WI + x] : 0.f;
}

// Fused wave-streaming kernel: one wave = 64 raw cols (52 outputs) x 15 output
// rows, BOTH targets; gather computed once per pixel. Matrices built per-wave.
// Per-wave partial stores (distinct addresses, no atomics).
__global__ __launch_bounds__(256) void k_stream(const float* __restrict__ focal,
                                                const float* __restrict__ aa,
                                                const float* __restrict__ cen,
                                                const float* __restrict__ depth,
                                                const float* __restrict__ ref,
                                                const float* __restrict__ tgts,
                                                float* __restrict__ partials) {
  const int wid = blockIdx.x*4 + (threadIdx.x >> 6);
  const int ln = threadIdx.x & 63;
  const int g = wid % NG, st = wid / NG;
  const int R0 = st * SROWS;
  const int x = g*GCOLS - 6 + ln;
  const bool xok = (x >= 0) && (x < WI);

  const float f = focal[0];
  float M[24];
  make_mats(f, aa, cen, M);

  float dring[7], rring[7];
  h2 wring[7];
  float Hr[7], H0[7], H1[7];
  float Qrr[7], Qrt0[7], Qtt0[7], Qrt1[7], Qtt1[7];
  const h2 hz = {(__fp16)0.f, (__fp16)0.f};
#pragma unroll
  for (int k = 0; k < 7; ++k) {
    dring[k]=0.f; rring[k]=0.f; wring[k]=hz;
    Hr[k]=0.f; H0[k]=0.f; H1[k]=0.f;
    Qrr[k]=0.f; Qrt0[k]=0.f; Qtt0[k]=0.f; Qrt1[k]=0.f; Qtt1[k]=0.f;
  }
  float Sr=0.f, S0=0.f, S1=0.f;
  float Vrr=0.f, Vrt0=0.f, Vtt0=0.f, Vrt1=0.f, Vtt1=0.f;
  float acc_s=0.f, acc_c=0.f;

  // prime depth ring: rows R0-7 (slot 6) and R0-6 (slot 0)
  dring[6] = loadI(depth, x, R0-7);
  dring[0] = loadI(depth, x, R0-6);

  for (int ib = 0; ib < PROWS; ib += 7) {
#pragma unroll
    for (int j = 0; j < 7; ++j) {
      const int y = R0 - 6 + ib + j;
      dring[(j+1)%7] = loadI(depth, x, y+1);

      // ---- warp + gather at (x,y), once per pixel ----
      float r = 0.f, w0 = 0.f, w1 = 0.f;
      if (xok && y >= 0 && y < HI) {
        const int gidx = y*WI + x;
        r = ref[gidx];
        float d  = dring[j];
        float dm = (x > 0)    ? depth[gidx-1] : 0.f;
        float dp = (x < WI-1) ? depth[gidx+1] : 0.f;
        float du = 0.5f*(dp - dm);
        float dv = 0.5f*(dring[(j+1)%7] - dring[(j+6)%7]);
        float fx = (float)x, fy = (float)y;
        float nx = f*du, ny = f*dv;
        float nz = (960.f - fx)*du + (720.f - fy)*dv - d;
        float nn = sqrtf(nx*nx + ny*ny + nz*nz) + EPSF;
        float wsc = 1.f/(nn*(d + EPSF));
        float px = (fx - 959.5f)/f, py = (fy - 719.5f)/f;
        float sv = (nx*px + ny*py + nz)*wsc;
        {
          float a0 = M[0]*fx + M[1]*fy + M[2] + M[9]*sv;
          float a1 = M[3]*fx + M[4]*fy + M[5] + M[10]*sv;
          float a2 = M[6]*fx + M[7]*fy + M[8] + M[11]*sv;
          float iz = 1.f/(a2 + EPSF);
          w0 = bilerp(tgts, a0*iz, a1*iz);
        }
        {
          float a0 = M[12]*fx + M[13]*fy + M[14] + M[21]*sv;
          float a1 = M[15]*fx + M[16]*fy + M[17] + M[22]*sv;
          float a2 = M[18]*fx + M[19]*fy + M[20] + M[23]*sv;
          float iz = 1.f/(a2 + EPSF);
          w1 = bilerp(tgts + NPIX, a0*iz, a1*iz);
        }
      }
      rring[j] = r;
      h2 wp = __builtin_amdgcn_cvt_pkrtz(w0, w1);
      wring[j] = wp;

      // ---- horizontal 7-sums of raw planes ----
      float hr = hsum7(r, ln);
      h2 hw = hsum7p(wp, ln);
      float h0 = (float)hw.x, h1 = (float)hw.y;

      // ---- vertical running box sums; box complete at yc = y-3 ----
      Sr += hr; S0 += h0; S1 += h1;
      const float Br = Sr, B0 = S0, B1 = S1;
      Sr -= Hr[(j+1)%7]; S0 -= H0[(j+1)%7]; S1 -= H1[(j+1)%7];
      Hr[j] = hr; H0[j] = h0; H1[j] = h1;

      // ---- centered values at row yc ----
      const int yc = y - 3;
      float cr = 0.f, c0 = 0.f, c1 = 0.f;
      if (xok && yc >= 0 && yc < HI) {
        h2 wc = wring[(j+4)%7];
        cr = rring[(j+4)%7] - Br*(1.f/49.f);
        c0 = (float)wc.x - B0*(1.f/49.f);
        c1 = (float)wc.y - B1*(1.f/49.f);
      }

      // ---- product horizontal 7-sums ----
      float prr = hsum7(cr*cr, ln);
      h2 q0 = hsum7p(__builtin_amdgcn_cvt_pkrtz(cr*c0, c0*c0), ln);
      h2 q1 = hsum7p(__builtin_amdgcn_cvt_pkrtz(cr*c1, c1*c1), ln);
      float hrt0 = (float)q0.x, htt0 = (float)q0.y;
      float hrt1 = (float)q1.x, htt1 = (float)q1.y;

      // ---- vertical running window sums; window complete at yo = y-6 ----
      Vrr += prr; Vrt0 += hrt0; Vtt0 += htt0; Vrt1 += hrt1; Vtt1 += htt1;

      const int yo = y - 6;
      if (yo >= R0 && yo < R0 + SROWS && ln >= 6 && ln <= 57 && x < WI) {
        const int mb = __builtin_bit_cast(int, wring[(j+1)%7]);  // raw w at row yo
        const float inv49 = 1.f/49.f;
        float vr = Vrr*inv49;
        if (mb & 0xffff) {
          float zm = (Vrt0*inv49) * rsqrtf(vr*(Vtt0*inv49) + EPSF);
          acc_s += zm; acc_c += 1.f;
        }
        if (((unsigned)mb >> 16) != 0u) {
          float zm = (Vrt1*inv49) * rsqrtf(vr*(Vtt1*inv49) + EPSF);
          acc_s += zm; acc_c += 1.f;
        }
      }

      Vrr -= Qrr[(j+5)%7]; Vrt0 -= Qrt0[(j+5)%7]; Vtt0 -= Qtt0[(j+5)%7];
      Vrt1 -= Qrt1[(j+5)%7]; Vtt1 -= Qtt1[(j+5)%7];
      Qrr[(j+4)%7] = prr; Qrt0[(j+4)%7] = hrt0; Qtt0[(j+4)%7] = htt0;
      Qrt1[(j+4)%7] = hrt1; Qtt1[(j+4)%7] = htt1;
    }
  }

  // ---- wave reduce, one partial pair per wave (distinct addresses) ----
#pragma unroll
  for (int off = 32; off > 0; off >>= 1) {
    acc_s += __shfl_down(acc_s, off, 64);
    acc_c += __shfl_down(acc_c, off, 64);
  }
  if (ln == 0) { partials[2*wid] = acc_s; partials[2*wid+1] = acc_c; }
}

__global__ __launch_bounds__(256) void k_final(const float* __restrict__ partials, int nb,
                                               float* __restrict__ out) {
  float s = 0.f, c = 0.f;
  for (int i = threadIdx.x; i < nb; i += 256) {
    s += partials[2*i];
    c += partials[2*i+1];
  }
#pragma unroll
  for (int off = 32; off > 0; off >>= 1) {
    s += __shfl_down(s, off, 64);
    c += __shfl_down(c, off, 64);
  }
  __shared__ float red[8];
  int tid = threadIdx.x;
  if ((tid & 63) == 0) { red[(tid>>6)*2] = s; red[(tid>>6)*2+1] = c; }
  __syncthreads();
  if (tid == 0) {
    float S = red[0]+red[2]+red[4]+red[6];
    float C = red[1]+red[3]+red[5]+red[7];
    float mean = S / fmaxf(C, 1.f);
    out[0] = (C > 0.f) ? 0.5f*(1.f - mean) : 0.f;
  }
}

extern "C" void kernel_launch(void* const* d_in, const int* in_sizes, int n_in,
                              void* d_out, int out_size, void* d_ws, size_t ws_size,
                              hipStream_t stream) {
  const float* focal  = (const float*)d_in[0];
  const float* aa     = (const float*)d_in[1];
  const float* cen    = (const float*)d_in[2];
  const float* ref    = (const float*)d_in[3];
  const float* depth  = (const float*)d_in[4];
  const float* tgts   = (const float*)d_in[5];
  float* out = (float*)d_out;

  float* partials = (float*)d_ws;     // 2 * NWAVES

  k_stream<<<NWAVES/4, 256, 0, stream>>>(focal, aa, cen, depth, ref, tgts, partials);
  k_final<<<1, 256, 0, stream>>>(partials, NWAVES, out);
}